// Round 6
// baseline (402.177 us; speedup 1.0000x reference)
//
#include <hip/hip_runtime.h>
#include <hip/hip_fp16.h>

#define S_LEN 4096
#define NT 256
#define RANK 8
#define AP 4352   // padded FFT scratch (transpose-2 max addr 4350)

__device__ __forceinline__ float rfl(float v){
    return __int_as_float(__builtin_amdgcn_readfirstlane(__float_as_int(v)));
}

__device__ __forceinline__ void cmul(float& xr, float& xi, float cr, float ci){
    float tr = xr*cr - xi*ci;
    xi = xr*ci + xi*cr;
    xr = tr;
}

template<int SIGN>
__device__ __forceinline__ void dft4(float& ar,float& ai,float& br,float& bi,
                                     float& cr,float& ci,float& dr,float& di){
    float Ar=ar+cr, Ai=ai+ci;
    float Br=ar-cr, Bi=ai-ci;
    float Cr=br+dr, Ci=bi+di;
    float Dr, Di;
    if (SIGN < 0){ Dr = bi-di; Di = dr-br; }
    else         { Dr = di-bi; Di = br-dr; }
    ar=Ar+Cr; ai=Ai+Ci;
    br=Br+Dr; bi=Bi+Di;
    cr=Ar-Cr; ci=Ai-Ci;
    dr=Br-Dr; di=Bi-Di;
}

// 16-pt DFT in regs; input natural order, output X[k] at slot 4*(k&3)+(k>>2)
template<int SIGN>
__device__ __forceinline__ void dft16(float ur[16], float ui[16]){
    constexpr float TC[10] = {1.0f, 0.92387953251128674f, 0.70710678118654752f,
                              0.38268343236508977f, 0.0f, -0.38268343236508977f,
                              -0.70710678118654752f, -0.92387953251128674f, -1.0f,
                              -0.92387953251128674f};
    constexpr float TS[10] = {0.0f, 0.38268343236508977f, 0.70710678118654752f,
                              0.92387953251128674f, 1.0f, 0.92387953251128674f,
                              0.70710678118654752f, 0.38268343236508977f, 0.0f,
                              -0.38268343236508977f};
#pragma unroll
    for (int p=0;p<4;p++)
        dft4<SIGN>(ur[p],ui[p], ur[p+4],ui[p+4], ur[p+8],ui[p+8], ur[p+12],ui[p+12]);
#pragma unroll
    for (int j=1;j<4;j++){
#pragma unroll
        for (int p=1;p<4;p++){
            const int e = p*j;
            const float c = TC[e];
            const float s = (SIGN < 0) ? -TS[e] : TS[e];
            cmul(ur[4*j+p], ui[4*j+p], c, s);
        }
    }
#pragma unroll
    for (int j=0;j<4;j++)
        dft4<SIGN>(ur[4*j+0],ui[4*j+0], ur[4*j+1],ui[4*j+1],
                   ur[4*j+2],ui[4*j+2], ur[4*j+3],ui[4*j+3]);
}

template<int SIGN>
__device__ __forceinline__ void twiddle_powers(float ur[16], float ui[16], float theta){
    float s, c;
    __sincosf(theta, &s, &c);
    const float wi = (SIGN < 0) ? -s : s;
    const float wr = c;
    float pr = wr, pi = wi;
    cmul(ur[1], ui[1], pr, pi);
#pragma unroll
    for (int m=2;m<16;m++){
        float nr = pr*wr - pi*wi;
        pi = pr*wi + pi*wr;
        pr = nr;
        cmul(ur[m], ui[m], pr, pi);
    }
}

// base spectral gain + interpolation setup (symmetric in k <-> S-k)
__device__ __forceinline__ void gain_setup(int k, float& bg, int& lo, int& hi, float& fr){
    const int m = (k < S_LEN - k) ? k : (S_LEN - k);
    const float nf = (float)(2 * m) * (1.0f / (float)S_LEN);
    const float tt = nf * 5.0f;
    const float lb = __expf(-0.5f * tt * tt);
    const float hd = 0.5f / (1.0f + __expf(-(nf - 0.6f) * 10.0f));
    bg = fmaxf(1.0f + lb - hd, 0.0f);
    const float scaled = nf * 4095.0f;
    const float fl = floorf(scaled);
    lo = (int)fl;
    hi = (int)ceilf(scaled);
    fr = scaled - fl;
}

__global__ __launch_bounds__(NT, 3) void recip_mixer(
    const float* __restrict__ x,
    const float* __restrict__ Ur, const float* __restrict__ Ui,
    const float* __restrict__ Vr, const float* __restrict__ Vi,
    const float* __restrict__ Wr, const float* __restrict__ Wi,
    const float* __restrict__ P1w, const float* __restrict__ P1b,
    const float* __restrict__ P2w, const float* __restrict__ P2b,
    const float* __restrict__ alphap,
    float* __restrict__ out)
{
    __shared__ float sre[AP], sim[AP];
    __shared__ __half gA[S_LEN], gB[S_LEN];
    __shared__ float red[128];
    __shared__ float hid[2 * RANK];
    __shared__ float gam[4 * RANK];

    const int t    = threadIdx.x;
    const int pair = blockIdx.x;           // rows 2*pair, 2*pair+1
    const int lane = t & 63;
    const int wid  = t >> 6;
    const int half = t >> 7;               // 0: row a, 1: row b (wave-uniform)
    const int th   = t & 127;

    const float alpha = alphap[0];

    float ur[16], ui[16];

    // ============ forward FFT of c = xa + i*xb (one FFT, two rows) ============
    {
        const float* xa = x + (size_t)(2 * pair) * S_LEN;
        const float* xb = xa + S_LEN;
#pragma unroll
        for (int c=0;c<16;c++){ ur[c] = xa[t + 256*c]; ui[c] = xb[t + 256*c]; }
        dft16<-1>(ur, ui);
        const int base1 = (t & 15) + 272 * (t >> 4);
#pragma unroll
        for (int k=0;k<16;k++){
            const int slot = 4*(k&3) + (k>>2);
            sre[base1 + 16*k] = ur[slot];
            sim[base1 + 16*k] = ui[slot];
        }
    }
    __syncthreads();
    {
        const int n1 = t & 15, k2p = t >> 4;
#pragma unroll
        for (int m=0;m<16;m++){
            ur[m] = sre[n1 + 272*m + 16*k2p];
            ui[m] = sim[n1 + 272*m + 16*k2p];
        }
        twiddle_powers<-1>(ur, ui, 6.2831853071795864769f * (float)k2p * (1.0f/256.0f));
        dft16<-1>(ur, ui);
        __syncthreads();
        const int base2 = k2p + 17*n1;
#pragma unroll
        for (int k=0;k<16;k++){
            const int slot = 4*(k&3) + (k>>2);
            sre[base2 + 272*k] = ur[slot];
            sim[base2 + 272*k] = ui[slot];
        }
    }
    __syncthreads();
    {
#pragma unroll
        for (int m=0;m<16;m++){
            ur[m] = sre[(t&15) + 17*m + 272*(t>>4)];
            ui[m] = sim[(t&15) + 17*m + 272*(t>>4)];
        }
        twiddle_powers<-1>(ur, ui, 6.2831853071795864769f * (float)t * (1.0f/4096.0f));
        dft16<-1>(ur, ui);
        __syncthreads();
#pragma unroll
        for (int k=0;k<16;k++){
            const int slot = 4*(k&3) + (k>>2);
            sre[t + 256*k] = ur[slot];
            sim[t + 256*k] = ui[slot];
        }
    }
    __syncthreads();

    // ============ M1: hidden, both rows, (k, S-k) paired ======================
    // X(rev)=conj(X) => h += XR*(w1k+w1r) + XI*(w2k-w2r)
    {
        float h[16];
#pragma unroll
        for (int j=0;j<16;j++) h[j] = 0.0f;
#pragma unroll 1
        for (int j=0;j<8;j++){
            const int k   = 1 + t + 256*j;       // 1..2048
            const int rev = S_LEN - k;
            const float sel = (k != rev) ? 1.0f : 0.0f;
            const float ZkR = sre[k],   ZkI = sim[k];
            const float ZrR = sre[rev], ZrI = sim[rev];
            const float XaR = 0.5f*(ZkR + ZrR), XaI = 0.5f*(ZkI - ZrI);
            const float XbR = 0.5f*(ZkI + ZrI), XbI = 0.5f*(ZrR - ZkR);
#pragma unroll
            for (int r=0;r<RANK;r++){
                const float w1k = P1w[r * (2*S_LEN) + k];
                const float w2k = P1w[r * (2*S_LEN) + S_LEN + k];
                const float w1r = P1w[r * (2*S_LEN) + rev];
                const float w2r = P1w[r * (2*S_LEN) + S_LEN + rev];
                const float A1 = fmaf(sel,  w1r, w1k);
                const float A2 = fmaf(-sel, w2r, w2k);
                h[r]     += XaR * A1 + XaI * A2;
                h[8 + r] += XbR * A1 + XbI * A2;
            }
        }
        if (t == 0){   // k = 0 self-pair: Xa=(Z0R,0), Xb=(Z0I,0)
            const float Z0R = sre[0], Z0I = sim[0];
#pragma unroll
            for (int r=0;r<RANK;r++){
                const float w1 = P1w[r * (2*S_LEN)];
                h[r]     += Z0R * w1;
                h[8 + r] += Z0I * w1;
            }
        }
#pragma unroll
        for (int j=0;j<16;j++){
#pragma unroll
            for (int off = 32; off > 0; off >>= 1)
                h[j] += __shfl_xor(h[j], off, 64);
        }
        if (lane == 0){
#pragma unroll
            for (int j=0;j<16;j++) red[wid*16 + j] = h[j];
        }
        __syncthreads();
        if (t < 16){
            float v = red[t] + red[16 + t] + red[32 + t] + red[48 + t];
            hid[t] = fmaxf(v + P1b[t & 7], 0.0f);
        }
        __syncthreads();
    }

    // ============ M2: paired gains + p/q accumulation, wave-split rows =======
    // waves 0-1: row a; waves 2-3: row b. g(rev)=g(k); z(rev)=g*conj(X).
    {
        float hh[RANK];
#pragma unroll
        for (int r=0;r<RANK;r++) hh[r] = rfl(hid[half*8 + r]);
        __half* gst = (half == 0) ? gA : gB;

        float acc[32];   // [pR x8, pI x8, qR x8, qI x8]
#pragma unroll
        for (int j=0;j<32;j++) acc[j] = 0.0f;

#pragma unroll 1
        for (int j=0;j<16;j++){
            const int k   = 1 + th + 128*j;      // 1..2048
            const int rev = S_LEN - k;
            const float sel = (k != rev) ? 1.0f : 0.0f;
            const float ZkR = sre[k],   ZkI = sim[k];
            const float ZrR = sre[rev], ZrI = sim[rev];
            float XR, XI;
            if (half == 0){ XR = 0.5f*(ZkR + ZrR); XI = 0.5f*(ZkI - ZrI); }
            else          { XR = 0.5f*(ZkI + ZrI); XI = 0.5f*(ZrR - ZkR); }

            float bg, fr; int lo, hi;
            gain_setup(k, bg, lo, hi, fr);
            const float4* p2lo = (const float4*)(P2w + (size_t)lo * RANK);
            const float4* p2hi = (const float4*)(P2w + (size_t)hi * RANK);
            const float4 a0 = p2lo[0], a1 = p2lo[1];
            const float4 b0 = p2hi[0], b1 = p2hi[1];
            const float dlo = P2b[lo] + hh[0]*a0.x + hh[1]*a0.y + hh[2]*a0.z + hh[3]*a0.w
                                      + hh[4]*a1.x + hh[5]*a1.y + hh[6]*a1.z + hh[7]*a1.w;
            const float dhi = P2b[hi] + hh[0]*b0.x + hh[1]*b0.y + hh[2]*b0.z + hh[3]*b0.w
                                      + hh[4]*b1.x + hh[5]*b1.y + hh[6]*b1.z + hh[7]*b1.w;
            const float g = fmaxf(bg + alpha * (dlo + (dhi - dlo) * fr), 0.0f);
            const __half gh = __float2half(g);
            gst[k] = gh;
            gst[rev] = gh;

            const float zR = g * XR, zI = g * XI;

#pragma unroll
            for (int r=0;r<RANK;r++){
                const float uRk = Ur[r*S_LEN + k],   uIk = Ui[r*S_LEN + k];
                const float uRr = Ur[r*S_LEN + rev], uIr = Ui[r*S_LEN + rev];
                const float uA1 = fmaf(sel,  uRr, uRk);
                const float uA2 = fmaf(-sel, uIr, uIk);
                const float uA3 = fmaf(sel,  uIr, uIk);
                const float uA4 = fmaf(-sel, uRr, uRk);
                acc[r]     += zR * uA1 - zI * uA2;
                acc[8 + r] += zR * uA3 + zI * uA4;
                const float vRk = Vr[r*S_LEN + k],   vIk = Vi[r*S_LEN + k];
                const float vRr = Vr[r*S_LEN + rev], vIr = Vi[r*S_LEN + rev];
                const float vA1 = fmaf(sel,  vRr, vRk);
                const float vA2 = fmaf(-sel, vIr, vIk);
                const float vA3 = fmaf(sel,  vIr, vIk);
                const float vA4 = fmaf(-sel, vRr, vRk);
                acc[16 + r] += zR * vA1 - zI * vA2;
                acc[24 + r] += zR * vA3 + zI * vA4;
            }
        }

        if (th == 0){   // k = 0 self-pair (one lane in wave 0, one in wave 2)
            const float Z0R = sre[0], Z0I = sim[0];
            const float XR = (half == 0) ? Z0R : Z0I;   // XI = 0
            float bg, fr; int lo, hi;
            gain_setup(0, bg, lo, hi, fr);
            const float4* p2lo = (const float4*)(P2w + (size_t)lo * RANK);
            const float4* p2hi = (const float4*)(P2w + (size_t)hi * RANK);
            const float4 a0 = p2lo[0], a1 = p2lo[1];
            const float4 b0 = p2hi[0], b1 = p2hi[1];
            const float dlo = P2b[lo] + hh[0]*a0.x + hh[1]*a0.y + hh[2]*a0.z + hh[3]*a0.w
                                      + hh[4]*a1.x + hh[5]*a1.y + hh[6]*a1.z + hh[7]*a1.w;
            const float dhi = P2b[hi] + hh[0]*b0.x + hh[1]*b0.y + hh[2]*b0.z + hh[3]*b0.w
                                      + hh[4]*b1.x + hh[5]*b1.y + hh[6]*b1.z + hh[7]*b1.w;
            const float g = fmaxf(bg + alpha * (dlo + (dhi - dlo) * fr), 0.0f);
            gst[0] = __float2half(g);
            const float zR = g * XR;
#pragma unroll
            for (int r=0;r<RANK;r++){
                acc[r]      += zR * Ur[r*S_LEN];
                acc[8 + r]  += zR * Ui[r*S_LEN];
                acc[16 + r] += zR * Vr[r*S_LEN];
                acc[24 + r] += zR * Vi[r*S_LEN];
            }
        }

#pragma unroll
        for (int j=0;j<32;j++){
#pragma unroll
            for (int off = 32; off > 0; off >>= 1)
                acc[j] += __shfl_xor(acc[j], off, 64);
        }
        if (lane == 0){
#pragma unroll
            for (int j=0;j<32;j++) red[wid*32 + j] = acc[j];
        }
        __syncthreads();
        if (t < RANK){
            const float pR = red[t]      + red[32 + t];
            const float pI = red[8 + t]  + red[40 + t];
            const float qR = red[16 + t] + red[48 + t];
            const float qI = red[24 + t] + red[56 + t];
            gam[t]     = pR * qR + pI * qI;   // Re gamma_a
            gam[8 + t] = pI * qR - pR * qI;   // Im gamma_a
        } else if (t < 2 * RANK){
            const int j = t - RANK;
            const float pR = red[64 + j] + red[96 + j];
            const float pI = red[72 + j] + red[104 + j];
            const float qR = red[80 + j] + red[112 + j];
            const float qI = red[88 + j] + red[120 + j];
            gam[16 + j] = pR * qR + pI * qI;  // Re gamma_b
            gam[24 + j] = pI * qR - pR * qI;  // Im gamma_b
        }
        __syncthreads();
    }

    // ============ M4 pass A: w-base = ga*Xa + i*gb*Xb (gains from LDS) =======
    {
#pragma unroll 2
        for (int k1=0;k1<16;k1++){
            const int k   = t + 256*k1;
            const int rev = (S_LEN - k) & (S_LEN - 1);
            const float ZkR = sre[k],   ZkI = sim[k];
            const float ZrR = sre[rev], ZrI = sim[rev];
            const float XaR = 0.5f*(ZkR + ZrR), XaI = 0.5f*(ZkI - ZrI);
            const float XbR = 0.5f*(ZkI + ZrI), XbI = 0.5f*(ZrR - ZkR);
            const float ga = __half2float(gA[k]);
            const float gb = __half2float(gB[k]);
            ur[k1] = ga * XaR - gb * XbI;
            ui[k1] = ga * XaI + gb * XbR;
        }
    }
    __syncthreads();   // Z fully consumed; sre/sim now reusable for Y

    // ============ M4 pass B: Herm(gamma@W) via LDS-shared Y ===================
    {
        float gR[RANK], gI[RANK];
        const float4* Wr4 = (const float4*)Wr;
        const float4* Wi4 = (const float4*)Wi;

        // ---- round 1: Ya ----
#pragma unroll
        for (int r=0;r<RANK;r++){ gR[r] = rfl(gam[r]); gI[r] = rfl(gam[8 + r]); }
#pragma unroll 2
        for (int k1=0;k1<16;k1++){
            const int k = t + 256*k1;
            const float4 w0 = Wr4[k*2], w1 = Wr4[k*2+1];
            const float4 v0 = Wi4[k*2], v1 = Wi4[k*2+1];
            const float wr_[RANK] = { w0.x,w0.y,w0.z,w0.w, w1.x,w1.y,w1.z,w1.w };
            const float wi_[RANK] = { v0.x,v0.y,v0.z,v0.w, v1.x,v1.y,v1.z,v1.w };
            float YR = 0.f, YI = 0.f;
#pragma unroll
            for (int r=0;r<RANK;r++){
                YR += gR[r]*wr_[r] - gI[r]*wi_[r];
                YI += gR[r]*wi_[r] + gI[r]*wr_[r];
            }
            sre[k] = YR;
            sim[k] = YI;
        }
        __syncthreads();
#pragma unroll 2
        for (int k1=0;k1<16;k1++){
            const int k   = t + 256*k1;
            const int rev = (S_LEN - k) & (S_LEN - 1);
            ur[k1] += 0.5f * (sre[k] + sre[rev]);   // Re HermYa
            ui[k1] += 0.5f * (sim[k] - sim[rev]);   // Im HermYa
        }
        __syncthreads();

        // ---- round 2: Yb ----
#pragma unroll
        for (int r=0;r<RANK;r++){ gR[r] = rfl(gam[16 + r]); gI[r] = rfl(gam[24 + r]); }
#pragma unroll 2
        for (int k1=0;k1<16;k1++){
            const int k = t + 256*k1;
            const float4 w0 = Wr4[k*2], w1 = Wr4[k*2+1];
            const float4 v0 = Wi4[k*2], v1 = Wi4[k*2+1];
            const float wr_[RANK] = { w0.x,w0.y,w0.z,w0.w, w1.x,w1.y,w1.z,w1.w };
            const float wi_[RANK] = { v0.x,v0.y,v0.z,v0.w, v1.x,v1.y,v1.z,v1.w };
            float YR = 0.f, YI = 0.f;
#pragma unroll
            for (int r=0;r<RANK;r++){
                YR += gR[r]*wr_[r] - gI[r]*wi_[r];
                YI += gR[r]*wi_[r] + gI[r]*wr_[r];
            }
            sre[k] = YR;
            sim[k] = YI;
        }
        __syncthreads();
#pragma unroll 2
        for (int k1=0;k1<16;k1++){
            const int k   = t + 256*k1;
            const int rev = (S_LEN - k) & (S_LEN - 1);
            ur[k1] -= 0.5f * (sim[k] - sim[rev]);   // -Im HermYb
            ui[k1] += 0.5f * (sre[k] + sre[rev]);   // +Re HermYb
        }
    }

    // ============ inverse FFT of w: row a = Re, row b = Im ====================
    dft16<1>(ur, ui);
    __syncthreads();   // Y reads complete before scratch overwrite
    {
        const int base1 = (t & 15) + 272 * (t >> 4);
#pragma unroll
        for (int k=0;k<16;k++){
            const int slot = 4*(k&3) + (k>>2);
            sre[base1 + 16*k] = ur[slot];
            sim[base1 + 16*k] = ui[slot];
        }
    }
    __syncthreads();
    {
        const int a = t & 15, b = t >> 4;
#pragma unroll
        for (int m=0;m<16;m++){
            ur[m] = sre[a + 272*m + 16*b];
            ui[m] = sim[a + 272*m + 16*b];
        }
        twiddle_powers<1>(ur, ui, 6.2831853071795864769f * (float)b * (1.0f/256.0f));
        dft16<1>(ur, ui);
        __syncthreads();
        const int base2 = b + 17*a;
#pragma unroll
        for (int k=0;k<16;k++){
            const int slot = 4*(k&3) + (k>>2);
            sre[base2 + 272*k] = ur[slot];
            sim[base2 + 272*k] = ui[slot];
        }
    }
    __syncthreads();
    {
#pragma unroll
        for (int m=0;m<16;m++){
            ur[m] = sre[(t&15) + 17*m + 272*(t>>4)];
            ui[m] = sim[(t&15) + 17*m + 272*(t>>4)];
        }
        twiddle_powers<1>(ur, ui, 6.2831853071795864769f * (float)t * (1.0f/4096.0f));
        dft16<1>(ur, ui);
        float* orowA = out + (size_t)(2 * pair) * S_LEN;
        float* orowB = orowA + S_LEN;
        const float scale = 1.0f / (float)S_LEN;
#pragma unroll
        for (int k=0;k<16;k++){
            const int slot = 4*(k&3) + (k>>2);
            orowA[t + 256*k] = ur[slot] * scale;
            orowB[t + 256*k] = ui[slot] * scale;
        }
    }
}

extern "C" void kernel_launch(void* const* d_in, const int* in_sizes, int n_in,
                              void* d_out, int out_size, void* d_ws, size_t ws_size,
                              hipStream_t stream) {
    const float* x    = (const float*)d_in[0];
    const float* Ur   = (const float*)d_in[1];
    const float* Ui   = (const float*)d_in[2];
    const float* Vr   = (const float*)d_in[3];
    const float* Vi   = (const float*)d_in[4];
    const float* Wr   = (const float*)d_in[5];
    const float* Wi   = (const float*)d_in[6];
    const float* P1w  = (const float*)d_in[7];
    const float* P1b  = (const float*)d_in[8];
    const float* P2w  = (const float*)d_in[9];
    const float* P2b  = (const float*)d_in[10];
    const float* alph = (const float*)d_in[11];

    recip_mixer<<<dim3(1024), dim3(NT), 0, stream>>>(
        x, Ur, Ui, Vr, Vi, Wr, Wi, P1w, P1b, P2w, P2b, alph, (float*)d_out);
}

// Round 7
// 262.408 us; speedup vs baseline: 1.5326x; 1.5326x over previous
//
#include <hip/hip_runtime.h>

#define S_LEN 4096
#define NT 256
#define RANK 8
#define AP 4352   // padded FFT scratch (transpose-2 max addr 4350)

__device__ __forceinline__ float rfl(float v){
    return __int_as_float(__builtin_amdgcn_readfirstlane(__float_as_int(v)));
}

__device__ __forceinline__ void cmul(float& xr, float& xi, float cr, float ci){
    float tr = xr*cr - xi*ci;
    xi = xr*ci + xi*cr;
    xr = tr;
}

template<int SIGN>
__device__ __forceinline__ void dft4(float& ar,float& ai,float& br,float& bi,
                                     float& cr,float& ci,float& dr,float& di){
    float Ar=ar+cr, Ai=ai+ci;
    float Br=ar-cr, Bi=ai-ci;
    float Cr=br+dr, Ci=bi+di;
    float Dr, Di;
    if (SIGN < 0){ Dr = bi-di; Di = dr-br; }
    else         { Dr = di-bi; Di = br-dr; }
    ar=Ar+Cr; ai=Ai+Ci;
    br=Br+Dr; bi=Bi+Di;
    cr=Ar-Cr; ci=Ai-Ci;
    dr=Br-Dr; di=Bi-Di;
}

// 16-pt DFT in regs; input natural order, output X[k] at slot 4*(k&3)+(k>>2)
template<int SIGN>
__device__ __forceinline__ void dft16(float ur[16], float ui[16]){
    constexpr float TC[10] = {1.0f, 0.92387953251128674f, 0.70710678118654752f,
                              0.38268343236508977f, 0.0f, -0.38268343236508977f,
                              -0.70710678118654752f, -0.92387953251128674f, -1.0f,
                              -0.92387953251128674f};
    constexpr float TS[10] = {0.0f, 0.38268343236508977f, 0.70710678118654752f,
                              0.92387953251128674f, 1.0f, 0.92387953251128674f,
                              0.70710678118654752f, 0.38268343236508977f, 0.0f,
                              -0.38268343236508977f};
#pragma unroll
    for (int p=0;p<4;p++)
        dft4<SIGN>(ur[p],ui[p], ur[p+4],ui[p+4], ur[p+8],ui[p+8], ur[p+12],ui[p+12]);
#pragma unroll
    for (int j=1;j<4;j++){
#pragma unroll
        for (int p=1;p<4;p++){
            const int e = p*j;
            const float c = TC[e];
            const float s = (SIGN < 0) ? -TS[e] : TS[e];
            cmul(ur[4*j+p], ui[4*j+p], c, s);
        }
    }
#pragma unroll
    for (int j=0;j<4;j++)
        dft4<SIGN>(ur[4*j+0],ui[4*j+0], ur[4*j+1],ui[4*j+1],
                   ur[4*j+2],ui[4*j+2], ur[4*j+3],ui[4*j+3]);
}

template<int SIGN>
__device__ __forceinline__ void twiddle_powers(float ur[16], float ui[16], float theta){
    float s, c;
    __sincosf(theta, &s, &c);
    const float wi = (SIGN < 0) ? -s : s;
    const float wr = c;
    float pr = wr, pi = wi;
    cmul(ur[1], ui[1], pr, pi);
#pragma unroll
    for (int m=2;m<16;m++){
        float nr = pr*wr - pi*wi;
        pi = pr*wi + pi*wr;
        pr = nr;
        cmul(ur[m], ui[m], pr, pi);
    }
}

// base spectral gain + interpolation setup
__device__ __forceinline__ void gain_setup(int k, float& bg, int& lo, int& hi, float& fr){
    const int m = (k < S_LEN - k) ? k : (S_LEN - k);
    const float nf = (float)(2 * m) * (1.0f / (float)S_LEN);
    const float tt = nf * 5.0f;
    const float lb = __expf(-0.5f * tt * tt);
    const float hd = 0.5f / (1.0f + __expf(-(nf - 0.6f) * 10.0f));
    bg = fmaxf(1.0f + lb - hd, 0.0f);
    const float scaled = nf * 4095.0f;
    const float fl = floorf(scaled);
    lo = (int)fl;
    hi = (int)ceilf(scaled);
    fr = scaled - fl;
}

__global__ __launch_bounds__(NT, 3) void recip_mixer(
    const float* __restrict__ x,
    const float* __restrict__ Ur, const float* __restrict__ Ui,
    const float* __restrict__ Vr, const float* __restrict__ Vi,
    const float* __restrict__ Wr, const float* __restrict__ Wi,
    const float* __restrict__ P1w, const float* __restrict__ P1b,
    const float* __restrict__ P2w, const float* __restrict__ P2b,
    const float* __restrict__ alphap,
    float* __restrict__ out)
{
    __shared__ float sre[AP], sim[AP];
    __shared__ float red[128];
    __shared__ float hid[RANK];
    __shared__ float gam[2 * RANK];

    const int t    = threadIdx.x;
    const int row  = blockIdx.x;
    const int lane = t & 63;
    const int wid  = t >> 6;

    const float alpha = alphap[0];

    float ur[16], ui[16];

    // ============ forward FFT: natural in -> Z[t+256*k1] in regs =============
    {
        const float* xrow = x + (size_t)row * S_LEN;
#pragma unroll
        for (int c=0;c<16;c++){ ur[c] = xrow[t + 256*c]; ui[c] = 0.0f; }
        dft16<-1>(ur, ui);
        const int base1 = (t & 15) + 272 * (t >> 4);
#pragma unroll
        for (int k=0;k<16;k++){
            const int slot = 4*(k&3) + (k>>2);
            sre[base1 + 16*k] = ur[slot];
            sim[base1 + 16*k] = ui[slot];
        }
    }
    __syncthreads();
    {
        const int n1 = t & 15, k2p = t >> 4;
#pragma unroll
        for (int m=0;m<16;m++){
            ur[m] = sre[n1 + 272*m + 16*k2p];
            ui[m] = sim[n1 + 272*m + 16*k2p];
        }
        twiddle_powers<-1>(ur, ui, 6.2831853071795864769f * (float)k2p * (1.0f/256.0f));
        dft16<-1>(ur, ui);
        __syncthreads();
        const int base2 = k2p + 17*n1;
#pragma unroll
        for (int k=0;k<16;k++){
            const int slot = 4*(k&3) + (k>>2);
            sre[base2 + 272*k] = ur[slot];
            sim[base2 + 272*k] = ui[slot];
        }
    }
    __syncthreads();
    {
#pragma unroll
        for (int m=0;m<16;m++){
            ur[m] = sre[(t&15) + 17*m + 272*(t>>4)];
            ui[m] = sim[(t&15) + 17*m + 272*(t>>4)];
        }
        twiddle_powers<-1>(ur, ui, 6.2831853071795864769f * (float)t * (1.0f/4096.0f));
        dft16<-1>(ur, ui);
        // Z[t + 256*k1] now in register slot 4*(k1&3)+(k1>>2). NO LDS write.
    }

    // ============ M1: hidden = relu(P1w @ [Re Z ; Im Z] + P1b) ===============
    {
        float h[RANK];
#pragma unroll
        for (int r=0;r<RANK;r++) h[r] = 0.0f;
#pragma unroll 2
        for (int k1=0;k1<16;k1++){
            const int slot = 4*(k1&3) + (k1>>2);
            const int k = t + 256*k1;
            const float zr = ur[slot], zi = ui[slot];
#pragma unroll
            for (int r=0;r<RANK;r++){
                h[r] += zr * P1w[r * (2*S_LEN) + k]
                      + zi * P1w[r * (2*S_LEN) + S_LEN + k];
            }
        }
#pragma unroll
        for (int r=0;r<RANK;r++){
#pragma unroll
            for (int off = 32; off > 0; off >>= 1)
                h[r] += __shfl_xor(h[r], off, 64);
        }
        if (lane == 0){
#pragma unroll
            for (int r=0;r<RANK;r++) red[wid*RANK + r] = h[r];
        }
        __syncthreads();
        if (t < RANK){
            float v = red[t] + red[RANK + t] + red[2*RANK + t] + red[3*RANK + t];
            hid[t] = fmaxf(v + P1b[t], 0.0f);
        }
        __syncthreads();
    }

    // ============ M2: gain + scale Z in regs + p/q accumulation ==============
    {
        float hh[RANK];
#pragma unroll
        for (int r=0;r<RANK;r++) hh[r] = rfl(hid[r]);

        float acc[32];   // [pR x8, pI x8, qR x8, qI x8]
#pragma unroll
        for (int j=0;j<32;j++) acc[j] = 0.0f;

#pragma unroll 2
        for (int k1=0;k1<16;k1++){
            const int slot = 4*(k1&3) + (k1>>2);
            const int k = t + 256*k1;

            float bg, fr; int lo, hi;
            gain_setup(k, bg, lo, hi, fr);
            const float4* p2lo = (const float4*)(P2w + (size_t)lo * RANK);
            const float4* p2hi = (const float4*)(P2w + (size_t)hi * RANK);
            const float4 a0 = p2lo[0], a1 = p2lo[1];
            const float4 b0 = p2hi[0], b1 = p2hi[1];
            const float dlo = P2b[lo] + hh[0]*a0.x + hh[1]*a0.y + hh[2]*a0.z + hh[3]*a0.w
                                      + hh[4]*a1.x + hh[5]*a1.y + hh[6]*a1.z + hh[7]*a1.w;
            const float dhi = P2b[hi] + hh[0]*b0.x + hh[1]*b0.y + hh[2]*b0.z + hh[3]*b0.w
                                      + hh[4]*b1.x + hh[5]*b1.y + hh[6]*b1.z + hh[7]*b1.w;
            const float g = fmaxf(bg + alpha * (dlo + (dhi - dlo) * fr), 0.0f);

            const float zR = g * ur[slot];
            const float zI = g * ui[slot];
            ur[slot] = zR;
            ui[slot] = zI;

#pragma unroll
            for (int r=0;r<RANK;r++){
                const float uR = Ur[r * S_LEN + k], uI = Ui[r * S_LEN + k];
                const float vR = Vr[r * S_LEN + k], vI = Vi[r * S_LEN + k];
                acc[r]      += zR * uR - zI * uI;
                acc[8 + r]  += zR * uI + zI * uR;
                acc[16 + r] += zR * vR - zI * vI;
                acc[24 + r] += zR * vI + zI * vR;
            }
        }

#pragma unroll
        for (int j=0;j<32;j++){
#pragma unroll
            for (int off = 32; off > 0; off >>= 1)
                acc[j] += __shfl_xor(acc[j], off, 64);
        }
        if (lane == 0){
#pragma unroll
            for (int j=0;j<32;j++) red[wid*32 + j] = acc[j];
        }
        __syncthreads();
        if (t < RANK){
            const float pR = red[t]      + red[32 + t] + red[64 + t]  + red[96 + t];
            const float pI = red[8 + t]  + red[40 + t] + red[72 + t]  + red[104 + t];
            const float qR = red[16 + t] + red[48 + t] + red[80 + t]  + red[112 + t];
            const float qI = red[24 + t] + red[56 + t] + red[88 + t]  + red[120 + t];
            gam[t]     = pR * qR + pI * qI;   // Re(p * conj(q))
            gam[8 + t] = pI * qR - pR * qI;   // Im(p * conj(q))
        }
        __syncthreads();
    }

    // ============ M4: z[k] += sum_r gamma[r] * W[k,r] (in regs) ==============
    {
        float gR[RANK], gI[RANK];
#pragma unroll
        for (int r=0;r<RANK;r++){ gR[r] = rfl(gam[r]); gI[r] = rfl(gam[8 + r]); }
        const float4* Wr4 = (const float4*)Wr;
        const float4* Wi4 = (const float4*)Wi;

#pragma unroll 2
        for (int k1=0;k1<16;k1++){
            const int slot = 4*(k1&3) + (k1>>2);
            const int k = t + 256*k1;
            const float4 w0 = Wr4[k*2], w1 = Wr4[k*2+1];
            const float4 v0 = Wi4[k*2], v1 = Wi4[k*2+1];
            const float wr_[RANK] = { w0.x,w0.y,w0.z,w0.w, w1.x,w1.y,w1.z,w1.w };
            const float wi_[RANK] = { v0.x,v0.y,v0.z,v0.w, v1.x,v1.y,v1.z,v1.w };
            float ar = 0.f, ai = 0.f;
#pragma unroll
            for (int r=0;r<RANK;r++){
                ar += gR[r]*wr_[r] - gI[r]*wi_[r];
                ai += gR[r]*wi_[r] + gI[r]*wr_[r];
            }
            ur[slot] += ar;
            ui[slot] += ai;
        }
    }

    // ============ permute slot layout -> natural order (involution swaps) ====
    {
        // slot(k) = 4*(k&3)+(k>>2); swap pairs (k, slot(k)) for k < slot(k)
#pragma unroll
        for (int k=0;k<16;k++){
            const int s = 4*(k&3) + (k>>2);
            if (k < s){
                float tr = ur[k]; ur[k] = ur[s]; ur[s] = tr;
                float ti = ui[k]; ui[k] = ui[s]; ui[s] = ti;
            }
        }
    }

    // ============ inverse FFT: w in regs (natural) -> out row =================
    dft16<1>(ur, ui);
    // last LDS reads (fwd round 3) were sequenced behind the M1/M2 barriers;
    // safe to overwrite scratch without an extra barrier.
    {
        const int base1 = (t & 15) + 272 * (t >> 4);
#pragma unroll
        for (int k=0;k<16;k++){
            const int slot = 4*(k&3) + (k>>2);
            sre[base1 + 16*k] = ur[slot];
            sim[base1 + 16*k] = ui[slot];
        }
    }
    __syncthreads();
    {
        const int a = t & 15, b = t >> 4;
#pragma unroll
        for (int m=0;m<16;m++){
            ur[m] = sre[a + 272*m + 16*b];
            ui[m] = sim[a + 272*m + 16*b];
        }
        twiddle_powers<1>(ur, ui, 6.2831853071795864769f * (float)b * (1.0f/256.0f));
        dft16<1>(ur, ui);
        __syncthreads();
        const int base2 = b + 17*a;
#pragma unroll
        for (int k=0;k<16;k++){
            const int slot = 4*(k&3) + (k>>2);
            sre[base2 + 272*k] = ur[slot];
            sim[base2 + 272*k] = ui[slot];
        }
    }
    __syncthreads();
    {
#pragma unroll
        for (int m=0;m<16;m++){
            ur[m] = sre[(t&15) + 17*m + 272*(t>>4)];
            ui[m] = sim[(t&15) + 17*m + 272*(t>>4)];
        }
        twiddle_powers<1>(ur, ui, 6.2831853071795864769f * (float)t * (1.0f/4096.0f));
        dft16<1>(ur, ui);
        float* orow = out + (size_t)row * S_LEN;
        const float scale = 1.0f / (float)S_LEN;
#pragma unroll
        for (int k=0;k<16;k++){
            const int slot = 4*(k&3) + (k>>2);
            orow[t + 256*k] = ur[slot] * scale;
        }
    }
}

extern "C" void kernel_launch(void* const* d_in, const int* in_sizes, int n_in,
                              void* d_out, int out_size, void* d_ws, size_t ws_size,
                              hipStream_t stream) {
    const float* x    = (const float*)d_in[0];
    const float* Ur   = (const float*)d_in[1];
    const float* Ui   = (const float*)d_in[2];
    const float* Vr   = (const float*)d_in[3];
    const float* Vi   = (const float*)d_in[4];
    const float* Wr   = (const float*)d_in[5];
    const float* Wi   = (const float*)d_in[6];
    const float* P1w  = (const float*)d_in[7];
    const float* P1b  = (const float*)d_in[8];
    const float* P2w  = (const float*)d_in[9];
    const float* P2b  = (const float*)d_in[10];
    const float* alph = (const float*)d_in[11];

    recip_mixer<<<dim3(2048), dim3(NT), 0, stream>>>(
        x, Ur, Ui, Vr, Vi, Wr, Wi, P1w, P1b, P2w, P2b, alph, (float*)d_out);
}